// Round 16
// baseline (348.779 us; speedup 1.0000x reference)
//
#include <hip/hip_runtime.h>
#include <cstdint>
#include <cstddef>

constexpr int BLK = 256;
constexpr int NB = 128;          // partition/pack blocks

static inline size_t ws_align(size_t x) { return (x + 255) & ~size_t(255); }

typedef __attribute__((ext_vector_type(8))) short bf16x8;
typedef __attribute__((ext_vector_type(4))) float f32x4;

__device__ inline unsigned short f2bf(float f) {
  unsigned int u = __float_as_uint(f);
  unsigned int r = (u + 0x7fffu + ((u >> 16) & 1u)) >> 16;   // RNE
  return (unsigned short)r;
}
__device__ inline float bf2f(unsigned short u) {
  return __uint_as_float(((unsigned int)u) << 16);
}
__device__ inline float bf2f_lo(unsigned int w) {
  return __uint_as_float(w << 16);
}
__device__ inline float bf2f_hi(unsigned int w) {
  return __uint_as_float(w & 0xffff0000u);
}

// async global->LDS, 16B per lane; lds dest wave-uniform base (+lane*16 implicit)
__device__ inline void gload16(const void* gp, void* lp) {
  __builtin_amdgcn_global_load_lds(
      (const __attribute__((address_space(1))) void*)gp,
      (__attribute__((address_space(3))) void*)lp, 16, 0, 0);
}

// ---------------- pack (+inline layout detect) + per-block window histogram + wt tail ----------------
// WT1: K-tile-major [16 tiles][128 wrow][32 k] (contiguous per-tile bursts).
// W3aT: [40 j][64 k] = W3[k][j] for k<64 (conv3 h2-part, consumed in-register).
__global__ void k_pack_wt(const int* __restrict__ ei, unsigned int* __restrict__ pk,
                          int* __restrict__ cnt, int E, int nChunk,
                          const float* __restrict__ W1, const float* __restrict__ W2,
                          const float* __restrict__ W3,
                          unsigned short* __restrict__ WT1, unsigned short* __restrict__ WT2,
                          unsigned short* __restrict__ W3aT) {
  if (blockIdx.x >= NB) {
    int i = (blockIdx.x - NB) * BLK + threadIdx.x;   // flat wt index
    if (i < 65536) {                 // WT1t: tile-major, linear
      int n = i >> 9, kg = i & 511;
      int tile = kg >> 5, k = kg & 31;
      WT1[tile * 4096 + n * 32 + k] = f2bf(W1[(size_t)kg * 128 + n]);
    } else if (i < 73728) {          // WT2: K=128, NOUT=64
      int j = i - 65536; int n = j >> 7, k = j & 127;
      WT2[j] = f2bf(W2[(size_t)k * 64 + n]);
    } else if (i < 76288) {          // W3aT: 40 x 64
      int j2 = i - 73728; int jj = j2 >> 6, k = j2 & 63;
      W3aT[j2] = f2bf(W3[(size_t)k * 40 + jj]);
    }
    return;
  }
  __shared__ int hist[256];
  for (int t = threadIdx.x; t < 256; t += BLK) hist[t] = 0;
  __syncthreads();
  int allz = 1;
  #pragma unroll 8
  for (int i = 0; i < 32; ++i) allz &= (ei[2 * i + 1] == 0) ? 1 : 0;
  const bool i64 = allz != 0;
  int beg = blockIdx.x * nChunk, end = min(beg + nChunk, E);
  for (int i = beg + threadIdx.x; i < end; i += BLK) {
    int row, col;
    if (i64) { row = ei[2 * i]; col = ei[2 * (E + i)]; }
    else     { row = ei[i];     col = ei[E + i]; }
    unsigned int p = ((unsigned int)col << 16) | (unsigned int)row;
    pk[i] = p;
    atomicAdd(&hist[col >> 8], 1);
  }
  __syncthreads();
  for (int t = threadIdx.x; t < 256; t += BLK) cnt[blockIdx.x * 256 + t] = hist[t];
}

// ---------------- wscan (block 0) + W3c precompute (blocks 1..4) ----------------
// WT3c[j][k] = (linW @ W3[64:128])[k][j], j<48 (pad), k<128 -> bf16
__global__ void k_wscan_w3c(const int* __restrict__ cnt, int* __restrict__ woffs,
                            int* __restrict__ base, int nb, int E,
                            const float* __restrict__ linW, const float* __restrict__ W3,
                            unsigned short* __restrict__ WT3c) {
  if (blockIdx.x > 0) {
    int jbase = ((int)blockIdx.x - 1) * 12;
    for (int idx = threadIdx.x; idx < 12 * 128; idx += BLK) {
      int j = jbase + (idx >> 7), k = idx & 127;
      if (j >= 48) continue;
      float v = 0.f;
      if (j < 40) {
        const float* lrow = linW + (size_t)k * 64;
        #pragma unroll 8
        for (int t = 0; t < 64; ++t) v += lrow[t] * W3[(size_t)(64 + t) * 40 + j];
      }
      WT3c[(size_t)j * 128 + k] = f2bf(v);
    }
    return;
  }
  __shared__ int wsums[5];
  int w = threadIdx.x;
  int s = 0;
  for (int b = 0; b < nb; ++b) s += cnt[b * 256 + w];
  int lane = w & 63, wv = w >> 6;
  int x = s;
  #pragma unroll
  for (int sh = 1; sh < 64; sh <<= 1) { int t = __shfl_up(x, sh); if (lane >= sh) x += t; }
  if (lane == 63) wsums[wv] = x;
  __syncthreads();
  if (w == 0) { int a = 0; for (int k = 0; k < 4; ++k) { int t = wsums[k]; wsums[k] = a; a += t; } }
  __syncthreads();
  int excl = x - s + wsums[wv];
  woffs[w] = excl;
  if (w == 255) woffs[256] = excl + s;   // == E
  int start = excl;
  for (int b = 0; b < nb; ++b) { base[b * 256 + w] = start; start += cnt[b * 256 + w]; }
}

// ---------------- small-K MFMA GEMM body (K=128) ----------------
template<int NT, int MR, bool AF32>
__device__ inline void mgemm_body(int bi, const void* __restrict__ Av,
                                  const unsigned short* __restrict__ WT,
                                  const float* __restrict__ dis, unsigned short* __restrict__ C,
                                  int ldc, int NOUT, int N) {
  constexpr int K = 128;
  const int tid = threadIdx.x;
  const int lane = tid & 63;
  const int wv = tid >> 6;
  const int m = lane & 15;
  const int kq = lane >> 4;
  const int orow = bi * (64 * MR) + wv * (16 * MR);

  int rowc[MR];
  #pragma unroll
  for (int mr = 0; mr < MR; ++mr) {
    int row = orow + mr * 16 + m;
    rowc[mr] = row < N ? row : N - 1;
  }

  f32x4 acc[MR][NT];
  #pragma unroll
  for (int mr = 0; mr < MR; ++mr)
    #pragma unroll
    for (int t = 0; t < NT; ++t) acc[mr][t] = {0.f, 0.f, 0.f, 0.f};

  #pragma unroll 4
  for (int k0 = 0; k0 < K; k0 += 32) {
    bf16x8 af[MR];
    #pragma unroll
    for (int mr = 0; mr < MR; ++mr) {
      if constexpr (AF32) {
        const float* Arow = (const float*)Av + (size_t)rowc[mr] * K + kq * 8 + k0;
        float4 a0 = *(const float4*)Arow;
        float4 a1 = *(const float4*)(Arow + 4);
        af[mr][0] = (short)f2bf(a0.x); af[mr][1] = (short)f2bf(a0.y);
        af[mr][2] = (short)f2bf(a0.z); af[mr][3] = (short)f2bf(a0.w);
        af[mr][4] = (short)f2bf(a1.x); af[mr][5] = (short)f2bf(a1.y);
        af[mr][6] = (short)f2bf(a1.z); af[mr][7] = (short)f2bf(a1.w);
      } else {
        const unsigned short* Arow = (const unsigned short*)Av + (size_t)rowc[mr] * K + kq * 8 + k0;
        af[mr] = *(const bf16x8*)Arow;
      }
    }
    bf16x8 bf[NT];
    #pragma unroll
    for (int t = 0; t < NT; ++t)
      bf[t] = *(const bf16x8*)(WT + (size_t)(t * 16 + m) * K + k0 + kq * 8);
    #pragma unroll
    for (int t = 0; t < NT; ++t)
      #pragma unroll
      for (int mr = 0; mr < MR; ++mr)
        acc[mr][t] = __builtin_amdgcn_mfma_f32_16x16x32_bf16(af[mr], bf[t], acc[mr][t], 0, 0, 0);
  }
  #pragma unroll
  for (int mr = 0; mr < MR; ++mr) {
    #pragma unroll
    for (int r = 0; r < 4; ++r) {
      int rr = orow + mr * 16 + kq * 4 + r;
      if (rr < N) {
        float s = dis ? dis[rr] : 1.f;
        #pragma unroll
        for (int t = 0; t < NT; ++t) {
          int cc = t * 16 + m;
          if (cc < NOUT)
            C[(size_t)rr * ldc + cc] = f2bf(acc[mr][t][r] * s);
        }
      }
    }
  }
}

// ---------------- merged: GEMM1 + partition scatter + spectral XP3 ----------------
// ranges: [0,gG1) gemm1 (F = x@W1, unscaled) ; [gG1,gG1+NB) scatter ; rest XP3 = eig@W3c
__global__ __launch_bounds__(256)
void k_part_gemm1(const unsigned int* __restrict__ pk, const int* __restrict__ base,
                  unsigned int* __restrict__ P, int E, int nChunk,
                  const float* __restrict__ x, const unsigned short* __restrict__ WT,
                  unsigned short* __restrict__ C, int N, int gG1,
                  const float* __restrict__ eig, const unsigned short* __restrict__ WT3c,
                  unsigned short* __restrict__ XP3) {
  __shared__ __align__(16) char smem[49152];   // 3 x (8KB A + 8KB W)
  if ((int)blockIdx.x >= gG1 + NB) {
    mgemm_body<3, 2, true>((int)blockIdx.x - gG1 - NB, eig, WT3c, nullptr, XP3, 40, 40, N);
    return;
  }
  if ((int)blockIdx.x >= gG1) {
    // ---- partition scatter ----
    const int pb = (int)blockIdx.x - gG1;
    int* cur = (int*)smem;
    for (int t = threadIdx.x; t < 256; t += BLK) cur[t] = base[pb * 256 + t];
    __syncthreads();
    int beg = pb * nChunk, end = min(beg + nChunk, E);
    for (int i = beg + threadIdx.x; i < end; i += BLK) {
      unsigned int p = pk[i];
      int pos = atomicAdd(&cur[p >> 24], 1);
      P[pos] = p;
    }
    return;
  }
  // ---- GEMM1: K=512, NOUT=128, 64 rows/block, 3-deep pipeline, counted vmcnt ----
  float* As0 = (float*)smem;                                   // 3 x 2048 floats
  unsigned short* Wsl0 = (unsigned short*)(smem + 24576);      // 3 x 4096 shorts
  const int tid = threadIdx.x;
  const int lane = tid & 63, wv = tid >> 6;
  const int m = lane & 15, kq = lane >> 4;
  const int row0 = (int)blockIdx.x * 64;

  const int r8 = lane >> 3;
  const int c8 = lane & 7;
  int agrow[2];
  #pragma unroll
  for (int jj = 0; jj < 2; ++jj) {
    int gr = row0 + wv * 16 + jj * 8 + r8;
    agrow[jj] = gr < N ? gr : N - 1;
  }

  f32x4 acc[8];
  #pragma unroll
  for (int t = 0; t < 8; ++t) acc[t] = {0.f, 0.f, 0.f, 0.f};

  auto STAGE = [&](int pb, int kb) {
    #pragma unroll
    for (int jj = 0; jj < 2; ++jj) {
      const float* src = x + (size_t)agrow[jj] * 512 + kb * 32 + (c8 ^ r8) * 4;
      gload16(src, As0 + pb * 2048 + (wv * 16 + jj * 8) * 32);
    }
    #pragma unroll
    for (int jj = 0; jj < 2; ++jj) {
      const unsigned short* src = WT + (size_t)kb * 4096 + wv * 1024 + jj * 512;
      gload16(src, Wsl0 + pb * 4096 + wv * 1024 + jj * 512);
    }
  };

  STAGE(0, 0);
  int cur = 0;
  #pragma unroll 1
  for (int t = 0; t < 16; ++t) {
    int nxt = cur + 1; if (nxt == 3) nxt = 0;
    if (t < 15) {
      STAGE(nxt, t + 1);
      asm volatile("s_waitcnt vmcnt(4)" ::: "memory");
    } else {
      asm volatile("s_waitcnt vmcnt(0)" ::: "memory");
    }
    __builtin_amdgcn_s_barrier();
    __builtin_amdgcn_sched_barrier(0);

    const char* Ab = (const char*)(As0 + cur * 2048);
    const char* Wb = (const char*)(Wsl0 + cur * 4096);
    const int row = wv * 16 + m;
    const int s = row & 7;
    f32x4 lo = *(const f32x4*)(Ab + row * 128 + ((kq * 2) ^ s) * 16);
    f32x4 hi = *(const f32x4*)(Ab + row * 128 + ((kq * 2 + 1) ^ s) * 16);
    bf16x8 af;
    af[0] = (short)f2bf(lo[0]); af[1] = (short)f2bf(lo[1]);
    af[2] = (short)f2bf(lo[2]); af[3] = (short)f2bf(lo[3]);
    af[4] = (short)f2bf(hi[0]); af[5] = (short)f2bf(hi[1]);
    af[6] = (short)f2bf(hi[2]); af[7] = (short)f2bf(hi[3]);
    #pragma unroll
    for (int tt = 0; tt < 8; ++tt) {
      int wrow = tt * 16 + m;
      bf16x8 bf = *(const bf16x8*)(Wb + wrow * 64 + kq * 16);
      acc[tt] = __builtin_amdgcn_mfma_f32_16x16x32_bf16(af, bf, acc[tt], 0, 0, 0);
    }
    cur = nxt;
  }

  #pragma unroll
  for (int r = 0; r < 4; ++r) {
    int rr = row0 + wv * 16 + kq * 4 + r;
    if (rr < N) {
      #pragma unroll
      for (int t = 0; t < 8; ++t)
        C[(size_t)rr * 128 + t * 16 + m] = f2bf(acc[t][r]);
    }
  }
}

// ---------------- per-window build: deg -> dis, offs, csr ----------------
__global__ void k_window_build(const unsigned int* __restrict__ P,
                               const int* __restrict__ woffs,
                               float* __restrict__ dis, int* __restrict__ offs,
                               int* __restrict__ csr, int N, int E) {
  __shared__ int hist[256];
  __shared__ int wsums[5];
  __shared__ int lbase[256];
  const int node0 = blockIdx.x * 256;
  const int t = threadIdx.x;
  hist[t] = 0;
  __syncthreads();
  const int beg = woffs[blockIdx.x], end = woffs[blockIdx.x + 1];
  for (int i = beg + t; i < end; i += BLK)
    atomicAdd(&hist[(P[i] >> 16) & 255], 1);
  __syncthreads();
  const int dg = hist[t];
  if (node0 + t < N) dis[node0 + t] = 1.0f / sqrtf((float)(dg + 1));
  int lane = t & 63, wv = t >> 6;
  int x = dg;
  #pragma unroll
  for (int sh = 1; sh < 64; sh <<= 1) { int q = __shfl_up(x, sh); if (lane >= sh) x += q; }
  if (lane == 63) wsums[wv] = x;
  __syncthreads();
  if (t == 0) { int a = 0; for (int k = 0; k < 4; ++k) { int q = wsums[k]; wsums[k] = a; a += q; } }
  __syncthreads();
  const int goff = beg + (x - dg + wsums[wv]);
  if (node0 + t < N) offs[node0 + t] = goff;
  lbase[t] = goff;
  __syncthreads();
  for (int i = beg + t; i < end; i += BLK) {
    unsigned int p = P[i];
    int pos = atomicAdd(&lbase[(p >> 16) & 255], 1);
    csr[pos] = (int)(p & 0xffffu);
  }
  if (blockIdx.x == 0 && t == 0) offs[N] = E;
}

// conv2 GEMM only: F2 = (G @ W2) * dis
__global__ __launch_bounds__(256)
void k_mgemm2(const unsigned short* __restrict__ G, const unsigned short* __restrict__ WT2,
              const float* __restrict__ dis, unsigned short* __restrict__ F2, int N) {
  mgemm_body<4, 2, false>(blockIdx.x, G, WT2, dis, F2, 64, 64, N);
}

// ---------------- aggregation: 32 lanes per row, 2 edges per load ----------------
template<int D, bool RELU, bool GDIS>
__launch_bounds__(BLK)
__global__ void k_agg2(const unsigned short* __restrict__ g, int ldg,
                       const float* __restrict__ dis, const float* __restrict__ bias,
                       const int* __restrict__ offs, const int* __restrict__ csr,
                       unsigned short* __restrict__ dst, int ldd, int N) {
  constexpr int CPL = D / 32;
  int wid = (blockIdx.x * BLK + threadIdx.x) >> 6;
  int lane = threadIdx.x & 63;
  if (wid >= N) return;
  const int l5 = lane >> 5, c = lane & 31;
  const float dv = dis[wid];
  float acc[CPL];
  #pragma unroll
  for (int k = 0; k < CPL; ++k) acc[k] = 0.f;

  auto addrow = [&](int r, float w) {
    if constexpr (CPL == 4) {
      uint2 v = *(const uint2*)&g[(size_t)r * ldg + c * 4];
      acc[0] = fmaf(w, bf2f_lo(v.x), acc[0]); acc[1] = fmaf(w, bf2f_hi(v.x), acc[1]);
      acc[2] = fmaf(w, bf2f_lo(v.y), acc[2]); acc[3] = fmaf(w, bf2f_hi(v.y), acc[3]);
    } else {
      unsigned int v = *(const unsigned int*)&g[(size_t)r * ldg + c * 2];
      acc[0] = fmaf(w, bf2f_lo(v), acc[0]); acc[1] = fmaf(w, bf2f_hi(v), acc[1]);
    }
  };

  if (l5 == 0) addrow(wid, GDIS ? dv : 1.0f);
  int beg = offs[wid], end = offs[wid + 1];
  for (int e0 = beg; e0 < end; e0 += 64) {
    int cnt = end - e0; if (cnt > 64) cnt = 64;
    int u = (lane < cnt) ? csr[e0 + lane] : 0;
    float du = 1.0f;
    if constexpr (GDIS) du = (lane < cnt) ? dis[u] : 0.f;
    int j = 0;
    for (; j + 3 < cnt; j += 4) {
      int r0 = __shfl(u, j + l5);
      int r1 = __shfl(u, j + 2 + l5);
      float w0 = GDIS ? __shfl(du, j + l5) : 1.0f;
      float w1 = GDIS ? __shfl(du, j + 2 + l5) : 1.0f;
      addrow(r0, w0); addrow(r1, w1);
    }
    for (; j < cnt; j += 2) {
      int jj = j + l5;
      int si = jj < cnt ? jj : j;
      int r0 = __shfl(u, si);
      float w0 = GDIS ? __shfl(du, si) : 1.0f;
      if (jj < cnt) addrow(r0, w0);
    }
  }
  #pragma unroll
  for (int k = 0; k < CPL; ++k) acc[k] += __shfl_xor(acc[k], 32);

  if (l5 == 0) {
    float o[CPL];
    #pragma unroll
    for (int k = 0; k < CPL; ++k) {
      o[k] = dv * acc[k] + bias[c * CPL + k];
      if constexpr (RELU) o[k] = fmaxf(o[k], 0.f);
    }
    if constexpr (CPL == 4) {
      uint2 pw;
      pw.x = (unsigned)f2bf(o[0]) | ((unsigned)f2bf(o[1]) << 16);
      pw.y = (unsigned)f2bf(o[2]) | ((unsigned)f2bf(o[3]) << 16);
      *(uint2*)&dst[(size_t)wid * ldd + c * 4] = pw;
    } else {
      unsigned int pw = (unsigned)f2bf(o[0]) | ((unsigned)f2bf(o[1]) << 16);
      *(unsigned int*)&dst[(size_t)wid * ldd + c * 2] = pw;
    }
  }
}

// ---------------- agg64 + fused conv3 row-GEMM: F3 = dis*(h2@W3a + XP3) ----------------
__launch_bounds__(BLK)
__global__ void k_agg64c3(const unsigned short* __restrict__ g,   // F2, N x 64
                          const float* __restrict__ dis, const float* __restrict__ b2,
                          const int* __restrict__ offs, const int* __restrict__ csr,
                          const unsigned short* __restrict__ W3aT, // 40 x 64
                          const unsigned short* __restrict__ XP3,  // N x 40
                          unsigned short* __restrict__ F3, int N) {
  int wid = (blockIdx.x * BLK + threadIdx.x) >> 6;
  int lane = threadIdx.x & 63;
  if (wid >= N) return;
  const int l5 = lane >> 5, c = lane & 31;
  const float dv = dis[wid];
  float a0 = 0.f, a1 = 0.f;

  auto addrow = [&](int r) {
    unsigned int v = *(const unsigned int*)&g[(size_t)r * 64 + c * 2];
    a0 += bf2f_lo(v); a1 += bf2f_hi(v);
  };

  if (l5 == 0) addrow(wid);
  int beg = offs[wid], end = offs[wid + 1];
  for (int e0 = beg; e0 < end; e0 += 64) {
    int cnt = end - e0; if (cnt > 64) cnt = 64;
    int u = (lane < cnt) ? csr[e0 + lane] : 0;
    int j = 0;
    for (; j + 3 < cnt; j += 4) {
      int r0 = __shfl(u, j + l5);
      int r1 = __shfl(u, j + 2 + l5);
      addrow(r0); addrow(r1);
    }
    for (; j < cnt; j += 2) {
      int jj = j + l5;
      int r0 = __shfl(u, jj < cnt ? jj : j);
      if (jj < cnt) addrow(r0);
    }
  }
  a0 += __shfl_xor(a0, 32);
  a1 += __shfl_xor(a1, 32);

  // h2 row: lane c (both halves) holds cols 2c, 2c+1
  float h0 = fmaxf(dv * a0 + b2[c * 2], 0.f);
  float h1v = fmaxf(dv * a1 + b2[c * 2 + 1], 0.f);

  // conv3: output j = l5*20 + c for c<20
  const bool act = c < 20;
  const int j = l5 * 20 + c;
  const unsigned int* wrow = (const unsigned int*)(W3aT + (size_t)(act ? j : 0) * 64);
  float wacc = 0.f;
  #pragma unroll
  for (int i = 0; i < 32; ++i) {
    float va = __shfl(h0, i, 32);
    float vb = __shfl(h1v, i, 32);
    unsigned int wp = wrow[i];
    wacc = fmaf(va, bf2f_lo(wp), wacc);
    wacc = fmaf(vb, bf2f_hi(wp), wacc);
  }
  if (act) {
    float xpv = bf2f(XP3[(size_t)wid * 40 + j]);
    F3[(size_t)wid * 40 + j] = f2bf(dv * (wacc + xpv));
  }
}

// ---------------- aggregation D=40 + log_softmax, fp32 out ----------------
__launch_bounds__(BLK)
__global__ void k_agg40(const unsigned short* __restrict__ g,
                        const float* __restrict__ dis, const float* __restrict__ bias,
                        const int* __restrict__ offs, const int* __restrict__ csr,
                        float* __restrict__ dst, int N) {
  int wid = (blockIdx.x * BLK + threadIdx.x) >> 6;
  int lane = threadIdx.x & 63;
  if (wid >= N) return;
  const int l5 = lane >> 5, c = lane & 31;
  const bool act = c < 20;
  float a0 = 0.f, a1 = 0.f;
  auto addrow = [&](int r) {
    if (act) {
      unsigned int w = *(const unsigned int*)&g[(size_t)r * 40 + c * 2];
      a0 += bf2f_lo(w); a1 += bf2f_hi(w);
    }
  };
  if (l5 == 0) addrow(wid);
  int beg = offs[wid], end = offs[wid + 1];
  for (int e0 = beg; e0 < end; e0 += 64) {
    int cnt = end - e0; if (cnt > 64) cnt = 64;
    int u = (lane < cnt) ? csr[e0 + lane] : 0;
    int j = 0;
    for (; j + 3 < cnt; j += 4) {
      int r0 = __shfl(u, j + l5);
      int r1 = __shfl(u, j + 2 + l5);
      addrow(r0); addrow(r1);
    }
    for (; j < cnt; j += 2) {
      int jj = j + l5;
      int r0 = __shfl(u, jj < cnt ? jj : j);
      if (jj < cnt) addrow(r0);
    }
  }
  a0 += __shfl_xor(a0, 32);
  a1 += __shfl_xor(a1, 32);

  if (l5 == 0) {
    float dv = dis[wid];
    float o0 = act ? dv * a0 + bias[c * 2]     : -__builtin_inff();
    float o1 = act ? dv * a1 + bias[c * 2 + 1] : -__builtin_inff();
    float mx = fmaxf(o0, o1);
    #pragma unroll
    for (int s = 16; s >= 1; s >>= 1) mx = fmaxf(mx, __shfl_down(mx, s, 32));
    mx = __shfl(mx, 0, 32);
    float ex = act ? (expf(o0 - mx) + expf(o1 - mx)) : 0.f;
    #pragma unroll
    for (int s = 16; s >= 1; s >>= 1) ex += __shfl_down(ex, s, 32);
    float ls = logf(__shfl(ex, 0, 32));
    if (act) {
      float2 r = make_float2(o0 - mx - ls, o1 - mx - ls);
      *(float2*)&dst[(size_t)wid * 40 + c * 2] = r;
    }
  }
}

// ---------------- launcher ----------------
extern "C" void kernel_launch(void* const* d_in, const int* in_sizes, int n_in,
                              void* d_out, int out_size, void* d_ws, size_t ws_size,
                              hipStream_t stream) {
  const float* x    = (const float*)d_in[0];
  const int*   ei   = (const int*)d_in[1];
  const float* eig  = (const float*)d_in[2];
  const float* W1   = (const float*)d_in[3];
  const float* b1   = (const float*)d_in[4];
  const float* W2   = (const float*)d_in[5];
  const float* b2   = (const float*)d_in[6];
  const float* linW = (const float*)d_in[7];
  const float* W3   = (const float*)d_in[8];
  const float* b3   = (const float*)d_in[9];
  float* out = (float*)d_out;

  const int N = in_sizes[0] / 512;
  const int E = in_sizes[1] / 2;

  char* ws = (char*)d_ws;
  size_t off = 0;
  auto alloc = [&](size_t bytes) { char* p = ws + off; off = ws_align(off + bytes); return p; };
  unsigned int* pk = (unsigned int*)alloc((size_t)E * 4);
  unsigned int* P  = (unsigned int*)alloc((size_t)E * 4);
  int*   csr    = (int*)alloc((size_t)E * 4);
  int*   offs   = (int*)alloc((size_t)(N + 1) * 4);
  int*   cnt    = (int*)alloc((size_t)NB * 256 * 4);
  int*   base   = (int*)alloc((size_t)NB * 256 * 4);
  int*   woffs  = (int*)alloc(257 * 4);
  float* dis    = (float*)alloc((size_t)N * 4);
  unsigned short* F   = (unsigned short*)alloc((size_t)N * 128 * 2);  // gemm1 out
  unsigned short* G   = (unsigned short*)alloc((size_t)N * 128 * 2);  // h1
  unsigned short* F2  = (unsigned short*)alloc((size_t)N * 64 * 2);   // conv2 out
  unsigned short* XP3 = (unsigned short*)alloc((size_t)N * 40 * 2);   // eig @ W3c
  unsigned short* F3  = (unsigned short*)alloc((size_t)N * 40 * 2);   // conv3 pre-agg
  unsigned short* WT1 = (unsigned short*)alloc(128 * 512 * 2);        // tile-major
  unsigned short* WT2 = (unsigned short*)alloc(64 * 128 * 2);
  unsigned short* W3aT = (unsigned short*)alloc(40 * 64 * 2);
  unsigned short* WT3c = (unsigned short*)alloc(48 * 128 * 2);

  const int nChunk = (E + NB - 1) / NB;
  const int NW = (N + 255) / 256;
  const int WTB = (76288 + BLK - 1) / BLK;
  const int gG1 = (N + 63) / 64;            // gemm1: 64 rows/block
  const int gX  = (N + 127) / 128;          // XP3 / mgemm2 blocks
  const int gA = (N + 3) / 4;

  k_pack_wt<<<NB + WTB, BLK, 0, stream>>>(ei, pk, cnt, E, nChunk,
                                          W1, W2, W3, WT1, WT2, W3aT);
  k_wscan_w3c<<<5, 256, 0, stream>>>(cnt, woffs, base, NB, E, linW, W3, WT3c);
  k_part_gemm1<<<gG1 + NB + gX, BLK, 0, stream>>>(pk, base, P, E, nChunk, x, WT1, F, N, gG1,
                                                  eig, WT3c, XP3);
  k_window_build<<<NW, BLK, 0, stream>>>(P, woffs, dis, offs, csr, N, E);

  // conv1 agg: h1 = relu(dis[v]*(sum du*g1[u] + dv*g1[v]) + b1)
  k_agg2<128, true, true><<<gA, BLK, 0, stream>>>(F, 128, dis, b1, offs, csr, G, 128, N);
  // conv2 GEMM
  k_mgemm2<<<gX, BLK, 0, stream>>>(G, WT2, dis, F2, N);
  // conv2 agg + fused conv3 GEMM (+XP3)
  k_agg64c3<<<gA, BLK, 0, stream>>>(F2, dis, b2, offs, csr, W3aT, XP3, F3, N);
  // conv3 agg + log_softmax
  k_agg40<<<gA, BLK, 0, stream>>>(F3, dis, b3, offs, csr, out, N);
}

// Round 17
// 280.020 us; speedup vs baseline: 1.2456x; 1.2456x over previous
//
#include <hip/hip_runtime.h>
#include <cstdint>
#include <cstddef>

constexpr int BLK = 256;
constexpr int NB = 128;          // partition/pack blocks

static inline size_t ws_align(size_t x) { return (x + 255) & ~size_t(255); }

typedef __attribute__((ext_vector_type(8))) short bf16x8;
typedef __attribute__((ext_vector_type(4))) float f32x4;

__device__ inline unsigned short f2bf(float f) {
  unsigned int u = __float_as_uint(f);
  unsigned int r = (u + 0x7fffu + ((u >> 16) & 1u)) >> 16;   // RNE
  return (unsigned short)r;
}
__device__ inline float bf2f(unsigned short u) {
  return __uint_as_float(((unsigned int)u) << 16);
}
__device__ inline float bf2f_lo(unsigned int w) {
  return __uint_as_float(w << 16);
}
__device__ inline float bf2f_hi(unsigned int w) {
  return __uint_as_float(w & 0xffff0000u);
}

// async global->LDS, 16B per lane; lds dest wave-uniform base (+lane*16 implicit)
__device__ inline void gload16(const void* gp, void* lp) {
  __builtin_amdgcn_global_load_lds(
      (const __attribute__((address_space(1))) void*)gp,
      (__attribute__((address_space(3))) void*)lp, 16, 0, 0);
}

// ---------------- pack (+inline layout detect) + per-block window histogram + wt tail ----------------
// WT1: K-tile-major [16 tiles][128 wrow][32 k] (contiguous per-tile bursts).
// W3aT: [48 j][64 k] = W3[k][j] (j<40, pad) — conv3 h2-part, MFMA B operand.
__global__ void k_pack_wt(const int* __restrict__ ei, unsigned int* __restrict__ pk,
                          int* __restrict__ cnt, int E, int nChunk,
                          const float* __restrict__ W1, const float* __restrict__ W2,
                          const float* __restrict__ W3,
                          unsigned short* __restrict__ WT1, unsigned short* __restrict__ WT2,
                          unsigned short* __restrict__ W3aT) {
  if (blockIdx.x >= NB) {
    int i = (blockIdx.x - NB) * BLK + threadIdx.x;   // flat wt index
    if (i < 65536) {                 // WT1t: tile-major, linear
      int n = i >> 9, kg = i & 511;
      int tile = kg >> 5, k = kg & 31;
      WT1[tile * 4096 + n * 32 + k] = f2bf(W1[(size_t)kg * 128 + n]);
    } else if (i < 73728) {          // WT2: K=128, NOUT=64
      int j = i - 65536; int n = j >> 7, k = j & 127;
      WT2[j] = f2bf(W2[(size_t)k * 64 + n]);
    } else if (i < 76800) {          // W3aT: 48 x 64 (pad rows 40..47)
      int j2 = i - 73728; int jj = j2 >> 6, k = j2 & 63;
      W3aT[j2] = f2bf(jj < 40 ? W3[(size_t)k * 40 + jj] : 0.f);
    }
    return;
  }
  __shared__ int hist[256];
  for (int t = threadIdx.x; t < 256; t += BLK) hist[t] = 0;
  __syncthreads();
  int allz = 1;
  #pragma unroll 8
  for (int i = 0; i < 32; ++i) allz &= (ei[2 * i + 1] == 0) ? 1 : 0;
  const bool i64 = allz != 0;
  int beg = blockIdx.x * nChunk, end = min(beg + nChunk, E);
  for (int i = beg + threadIdx.x; i < end; i += BLK) {
    int row, col;
    if (i64) { row = ei[2 * i]; col = ei[2 * (E + i)]; }
    else     { row = ei[i];     col = ei[E + i]; }
    unsigned int p = ((unsigned int)col << 16) | (unsigned int)row;
    pk[i] = p;
    atomicAdd(&hist[col >> 8], 1);
  }
  __syncthreads();
  for (int t = threadIdx.x; t < 256; t += BLK) cnt[blockIdx.x * 256 + t] = hist[t];
}

// ---------------- wscan (block 0) + W3c precompute (blocks 1..4) ----------------
// WT3c[j][k] = (linW @ W3[64:128])[k][j], j<48 (pad), k<128 -> bf16
__global__ void k_wscan_w3c(const int* __restrict__ cnt, int* __restrict__ woffs,
                            int* __restrict__ base, int nb, int E,
                            const float* __restrict__ linW, const float* __restrict__ W3,
                            unsigned short* __restrict__ WT3c) {
  if (blockIdx.x > 0) {
    int jbase = ((int)blockIdx.x - 1) * 12;
    for (int idx = threadIdx.x; idx < 12 * 128; idx += BLK) {
      int j = jbase + (idx >> 7), k = idx & 127;
      if (j >= 48) continue;
      float v = 0.f;
      if (j < 40) {
        const float* lrow = linW + (size_t)k * 64;
        #pragma unroll 8
        for (int t = 0; t < 64; ++t) v += lrow[t] * W3[(size_t)(64 + t) * 40 + j];
      }
      WT3c[(size_t)j * 128 + k] = f2bf(v);
    }
    return;
  }
  __shared__ int wsums[5];
  int w = threadIdx.x;
  int s = 0;
  for (int b = 0; b < nb; ++b) s += cnt[b * 256 + w];
  int lane = w & 63, wv = w >> 6;
  int x = s;
  #pragma unroll
  for (int sh = 1; sh < 64; sh <<= 1) { int t = __shfl_up(x, sh); if (lane >= sh) x += t; }
  if (lane == 63) wsums[wv] = x;
  __syncthreads();
  if (w == 0) { int a = 0; for (int k = 0; k < 4; ++k) { int t = wsums[k]; wsums[k] = a; a += t; } }
  __syncthreads();
  int excl = x - s + wsums[wv];
  woffs[w] = excl;
  if (w == 255) woffs[256] = excl + s;   // == E
  int start = excl;
  for (int b = 0; b < nb; ++b) { base[b * 256 + w] = start; start += cnt[b * 256 + w]; }
}

// ---------------- small-K MFMA GEMM body (K=128) ----------------
template<int NT, int MR, bool AF32>
__device__ inline void mgemm_body(int bi, const void* __restrict__ Av,
                                  const unsigned short* __restrict__ WT,
                                  const float* __restrict__ dis, unsigned short* __restrict__ C,
                                  int ldc, int NOUT, int N) {
  constexpr int K = 128;
  const int tid = threadIdx.x;
  const int lane = tid & 63;
  const int wv = tid >> 6;
  const int m = lane & 15;
  const int kq = lane >> 4;
  const int orow = bi * (64 * MR) + wv * (16 * MR);

  int rowc[MR];
  #pragma unroll
  for (int mr = 0; mr < MR; ++mr) {
    int row = orow + mr * 16 + m;
    rowc[mr] = row < N ? row : N - 1;
  }

  f32x4 acc[MR][NT];
  #pragma unroll
  for (int mr = 0; mr < MR; ++mr)
    #pragma unroll
    for (int t = 0; t < NT; ++t) acc[mr][t] = {0.f, 0.f, 0.f, 0.f};

  #pragma unroll 4
  for (int k0 = 0; k0 < K; k0 += 32) {
    bf16x8 af[MR];
    #pragma unroll
    for (int mr = 0; mr < MR; ++mr) {
      if constexpr (AF32) {
        const float* Arow = (const float*)Av + (size_t)rowc[mr] * K + kq * 8 + k0;
        float4 a0 = *(const float4*)Arow;
        float4 a1 = *(const float4*)(Arow + 4);
        af[mr][0] = (short)f2bf(a0.x); af[mr][1] = (short)f2bf(a0.y);
        af[mr][2] = (short)f2bf(a0.z); af[mr][3] = (short)f2bf(a0.w);
        af[mr][4] = (short)f2bf(a1.x); af[mr][5] = (short)f2bf(a1.y);
        af[mr][6] = (short)f2bf(a1.z); af[mr][7] = (short)f2bf(a1.w);
      } else {
        const unsigned short* Arow = (const unsigned short*)Av + (size_t)rowc[mr] * K + kq * 8 + k0;
        af[mr] = *(const bf16x8*)Arow;
      }
    }
    bf16x8 bf[NT];
    #pragma unroll
    for (int t = 0; t < NT; ++t)
      bf[t] = *(const bf16x8*)(WT + (size_t)(t * 16 + m) * K + k0 + kq * 8);
    #pragma unroll
    for (int t = 0; t < NT; ++t)
      #pragma unroll
      for (int mr = 0; mr < MR; ++mr)
        acc[mr][t] = __builtin_amdgcn_mfma_f32_16x16x32_bf16(af[mr], bf[t], acc[mr][t], 0, 0, 0);
  }
  #pragma unroll
  for (int mr = 0; mr < MR; ++mr) {
    #pragma unroll
    for (int r = 0; r < 4; ++r) {
      int rr = orow + mr * 16 + kq * 4 + r;
      if (rr < N) {
        float s = dis ? dis[rr] : 1.f;
        #pragma unroll
        for (int t = 0; t < NT; ++t) {
          int cc = t * 16 + m;
          if (cc < NOUT)
            C[(size_t)rr * ldc + cc] = f2bf(acc[mr][t][r] * s);
        }
      }
    }
  }
}

// ---------------- merged: GEMM1 + partition scatter + spectral XP3 ----------------
// ranges: [0,gG1) gemm1 (F = x@W1, unscaled) ; [gG1,gG1+NB) scatter ; rest XP3 = eig@W3c
__global__ __launch_bounds__(256)
void k_part_gemm1(const unsigned int* __restrict__ pk, const int* __restrict__ base,
                  unsigned int* __restrict__ P, int E, int nChunk,
                  const float* __restrict__ x, const unsigned short* __restrict__ WT,
                  unsigned short* __restrict__ C, int N, int gG1,
                  const float* __restrict__ eig, const unsigned short* __restrict__ WT3c,
                  unsigned short* __restrict__ XP3) {
  __shared__ __align__(16) char smem[49152];   // 3 x (8KB A + 8KB W)
  if ((int)blockIdx.x >= gG1 + NB) {
    mgemm_body<3, 2, true>((int)blockIdx.x - gG1 - NB, eig, WT3c, nullptr, XP3, 40, 40, N);
    return;
  }
  if ((int)blockIdx.x >= gG1) {
    // ---- partition scatter ----
    const int pb = (int)blockIdx.x - gG1;
    int* cur = (int*)smem;
    for (int t = threadIdx.x; t < 256; t += BLK) cur[t] = base[pb * 256 + t];
    __syncthreads();
    int beg = pb * nChunk, end = min(beg + nChunk, E);
    for (int i = beg + threadIdx.x; i < end; i += BLK) {
      unsigned int p = pk[i];
      int pos = atomicAdd(&cur[p >> 24], 1);
      P[pos] = p;
    }
    return;
  }
  // ---- GEMM1: K=512, NOUT=128, 64 rows/block, 3-deep pipeline, counted vmcnt ----
  float* As0 = (float*)smem;                                   // 3 x 2048 floats
  unsigned short* Wsl0 = (unsigned short*)(smem + 24576);      // 3 x 4096 shorts
  const int tid = threadIdx.x;
  const int lane = tid & 63, wv = tid >> 6;
  const int m = lane & 15, kq = lane >> 4;
  const int row0 = (int)blockIdx.x * 64;

  const int r8 = lane >> 3;
  const int c8 = lane & 7;
  int agrow[2];
  #pragma unroll
  for (int jj = 0; jj < 2; ++jj) {
    int gr = row0 + wv * 16 + jj * 8 + r8;
    agrow[jj] = gr < N ? gr : N - 1;
  }

  f32x4 acc[8];
  #pragma unroll
  for (int t = 0; t < 8; ++t) acc[t] = {0.f, 0.f, 0.f, 0.f};

  auto STAGE = [&](int pb, int kb) {
    #pragma unroll
    for (int jj = 0; jj < 2; ++jj) {
      const float* src = x + (size_t)agrow[jj] * 512 + kb * 32 + (c8 ^ r8) * 4;
      gload16(src, As0 + pb * 2048 + (wv * 16 + jj * 8) * 32);
    }
    #pragma unroll
    for (int jj = 0; jj < 2; ++jj) {
      const unsigned short* src = WT + (size_t)kb * 4096 + wv * 1024 + jj * 512;
      gload16(src, Wsl0 + pb * 4096 + wv * 1024 + jj * 512);
    }
  };

  STAGE(0, 0);
  int cur = 0;
  #pragma unroll 1
  for (int t = 0; t < 16; ++t) {
    int nxt = cur + 1; if (nxt == 3) nxt = 0;
    if (t < 15) {
      STAGE(nxt, t + 1);
      asm volatile("s_waitcnt vmcnt(4)" ::: "memory");
    } else {
      asm volatile("s_waitcnt vmcnt(0)" ::: "memory");
    }
    __builtin_amdgcn_s_barrier();
    __builtin_amdgcn_sched_barrier(0);

    const char* Ab = (const char*)(As0 + cur * 2048);
    const char* Wb = (const char*)(Wsl0 + cur * 4096);
    const int row = wv * 16 + m;
    const int s = row & 7;
    f32x4 lo = *(const f32x4*)(Ab + row * 128 + ((kq * 2) ^ s) * 16);
    f32x4 hi = *(const f32x4*)(Ab + row * 128 + ((kq * 2 + 1) ^ s) * 16);
    bf16x8 af;
    af[0] = (short)f2bf(lo[0]); af[1] = (short)f2bf(lo[1]);
    af[2] = (short)f2bf(lo[2]); af[3] = (short)f2bf(lo[3]);
    af[4] = (short)f2bf(hi[0]); af[5] = (short)f2bf(hi[1]);
    af[6] = (short)f2bf(hi[2]); af[7] = (short)f2bf(hi[3]);
    #pragma unroll
    for (int tt = 0; tt < 8; ++tt) {
      int wrow = tt * 16 + m;
      bf16x8 bf = *(const bf16x8*)(Wb + wrow * 64 + kq * 16);
      acc[tt] = __builtin_amdgcn_mfma_f32_16x16x32_bf16(af, bf, acc[tt], 0, 0, 0);
    }
    cur = nxt;
  }

  #pragma unroll
  for (int r = 0; r < 4; ++r) {
    int rr = row0 + wv * 16 + kq * 4 + r;
    if (rr < N) {
      #pragma unroll
      for (int t = 0; t < 8; ++t)
        C[(size_t)rr * 128 + t * 16 + m] = f2bf(acc[t][r]);
    }
  }
}

// ---------------- per-window build: deg -> dis, offs, csr ----------------
__global__ void k_window_build(const unsigned int* __restrict__ P,
                               const int* __restrict__ woffs,
                               float* __restrict__ dis, int* __restrict__ offs,
                               int* __restrict__ csr, int N, int E) {
  __shared__ int hist[256];
  __shared__ int wsums[5];
  __shared__ int lbase[256];
  const int node0 = blockIdx.x * 256;
  const int t = threadIdx.x;
  hist[t] = 0;
  __syncthreads();
  const int beg = woffs[blockIdx.x], end = woffs[blockIdx.x + 1];
  for (int i = beg + t; i < end; i += BLK)
    atomicAdd(&hist[(P[i] >> 16) & 255], 1);
  __syncthreads();
  const int dg = hist[t];
  if (node0 + t < N) dis[node0 + t] = 1.0f / sqrtf((float)(dg + 1));
  int lane = t & 63, wv = t >> 6;
  int x = dg;
  #pragma unroll
  for (int sh = 1; sh < 64; sh <<= 1) { int q = __shfl_up(x, sh); if (lane >= sh) x += q; }
  if (lane == 63) wsums[wv] = x;
  __syncthreads();
  if (t == 0) { int a = 0; for (int k = 0; k < 4; ++k) { int q = wsums[k]; wsums[k] = a; a += q; } }
  __syncthreads();
  const int goff = beg + (x - dg + wsums[wv]);
  if (node0 + t < N) offs[node0 + t] = goff;
  lbase[t] = goff;
  __syncthreads();
  for (int i = beg + t; i < end; i += BLK) {
    unsigned int p = P[i];
    int pos = atomicAdd(&lbase[(p >> 16) & 255], 1);
    csr[pos] = (int)(p & 0xffffu);
  }
  if (blockIdx.x == 0 && t == 0) offs[N] = E;
}

// conv2 GEMM only: F2 = (G @ W2) * dis
__global__ __launch_bounds__(256)
void k_mgemm2(const unsigned short* __restrict__ G, const unsigned short* __restrict__ WT2,
              const float* __restrict__ dis, unsigned short* __restrict__ F2, int N) {
  mgemm_body<4, 2, false>(blockIdx.x, G, WT2, dis, F2, 64, 64, N);
}

// conv3 GEMM: F3 = dis * (H2 @ W3a + XP3), K=64
__global__ __launch_bounds__(256)
void k_mgemm3b(const unsigned short* __restrict__ H2, const unsigned short* __restrict__ W3aT,
               const unsigned short* __restrict__ XP3, const float* __restrict__ dis,
               unsigned short* __restrict__ F3, int N) {
  constexpr int NT = 3, MR = 2, K = 64;
  const int tid = threadIdx.x;
  const int lane = tid & 63;
  const int wv = tid >> 6;
  const int m = lane & 15;
  const int kq = lane >> 4;
  const int orow = blockIdx.x * (64 * MR) + wv * (16 * MR);

  int rowc[MR];
  #pragma unroll
  for (int mr = 0; mr < MR; ++mr) {
    int row = orow + mr * 16 + m;
    rowc[mr] = row < N ? row : N - 1;
  }

  f32x4 acc[MR][NT];
  #pragma unroll
  for (int mr = 0; mr < MR; ++mr)
    #pragma unroll
    for (int t = 0; t < NT; ++t) acc[mr][t] = {0.f, 0.f, 0.f, 0.f};

  #pragma unroll
  for (int k0 = 0; k0 < K; k0 += 32) {
    bf16x8 af[MR];
    #pragma unroll
    for (int mr = 0; mr < MR; ++mr)
      af[mr] = *(const bf16x8*)(H2 + (size_t)rowc[mr] * 64 + kq * 8 + k0);
    bf16x8 bf[NT];
    #pragma unroll
    for (int t = 0; t < NT; ++t)
      bf[t] = *(const bf16x8*)(W3aT + (size_t)(t * 16 + m) * 64 + k0 + kq * 8);
    #pragma unroll
    for (int t = 0; t < NT; ++t)
      #pragma unroll
      for (int mr = 0; mr < MR; ++mr)
        acc[mr][t] = __builtin_amdgcn_mfma_f32_16x16x32_bf16(af[mr], bf[t], acc[mr][t], 0, 0, 0);
  }
  #pragma unroll
  for (int mr = 0; mr < MR; ++mr) {
    #pragma unroll
    for (int r = 0; r < 4; ++r) {
      int rr = orow + mr * 16 + kq * 4 + r;
      if (rr < N) {
        float s = dis[rr];
        #pragma unroll
        for (int t = 0; t < NT; ++t) {
          int cc = t * 16 + m;
          if (cc < 40) {
            float xpv = bf2f(XP3[(size_t)rr * 40 + cc]);
            F3[(size_t)rr * 40 + cc] = f2bf((acc[mr][t][r] + xpv) * s);
          }
        }
      }
    }
  }
}

// ---------------- aggregation: 32 lanes per row, 2 edges per load ----------------
template<int D, bool RELU, bool GDIS>
__launch_bounds__(BLK)
__global__ void k_agg2(const unsigned short* __restrict__ g, int ldg,
                       const float* __restrict__ dis, const float* __restrict__ bias,
                       const int* __restrict__ offs, const int* __restrict__ csr,
                       unsigned short* __restrict__ dst, int ldd, int N) {
  constexpr int CPL = D / 32;
  int wid = (blockIdx.x * BLK + threadIdx.x) >> 6;
  int lane = threadIdx.x & 63;
  if (wid >= N) return;
  const int l5 = lane >> 5, c = lane & 31;
  const float dv = dis[wid];
  float acc[CPL];
  #pragma unroll
  for (int k = 0; k < CPL; ++k) acc[k] = 0.f;

  auto addrow = [&](int r, float w) {
    if constexpr (CPL == 4) {
      uint2 v = *(const uint2*)&g[(size_t)r * ldg + c * 4];
      acc[0] = fmaf(w, bf2f_lo(v.x), acc[0]); acc[1] = fmaf(w, bf2f_hi(v.x), acc[1]);
      acc[2] = fmaf(w, bf2f_lo(v.y), acc[2]); acc[3] = fmaf(w, bf2f_hi(v.y), acc[3]);
    } else {
      unsigned int v = *(const unsigned int*)&g[(size_t)r * ldg + c * 2];
      acc[0] = fmaf(w, bf2f_lo(v), acc[0]); acc[1] = fmaf(w, bf2f_hi(v), acc[1]);
    }
  };

  if (l5 == 0) addrow(wid, GDIS ? dv : 1.0f);
  int beg = offs[wid], end = offs[wid + 1];
  for (int e0 = beg; e0 < end; e0 += 64) {
    int cnt = end - e0; if (cnt > 64) cnt = 64;
    int u = (lane < cnt) ? csr[e0 + lane] : 0;
    float du = 1.0f;
    if constexpr (GDIS) du = (lane < cnt) ? dis[u] : 0.f;
    int j = 0;
    for (; j + 3 < cnt; j += 4) {
      int r0 = __shfl(u, j + l5);
      int r1 = __shfl(u, j + 2 + l5);
      float w0 = GDIS ? __shfl(du, j + l5) : 1.0f;
      float w1 = GDIS ? __shfl(du, j + 2 + l5) : 1.0f;
      addrow(r0, w0); addrow(r1, w1);
    }
    for (; j < cnt; j += 2) {
      int jj = j + l5;
      int si = jj < cnt ? jj : j;
      int r0 = __shfl(u, si);
      float w0 = GDIS ? __shfl(du, si) : 1.0f;
      if (jj < cnt) addrow(r0, w0);
    }
  }
  #pragma unroll
  for (int k = 0; k < CPL; ++k) acc[k] += __shfl_xor(acc[k], 32);

  if (l5 == 0) {
    float o[CPL];
    #pragma unroll
    for (int k = 0; k < CPL; ++k) {
      o[k] = dv * acc[k] + bias[c * CPL + k];
      if constexpr (RELU) o[k] = fmaxf(o[k], 0.f);
    }
    if constexpr (CPL == 4) {
      uint2 pw;
      pw.x = (unsigned)f2bf(o[0]) | ((unsigned)f2bf(o[1]) << 16);
      pw.y = (unsigned)f2bf(o[2]) | ((unsigned)f2bf(o[3]) << 16);
      *(uint2*)&dst[(size_t)wid * ldd + c * 4] = pw;
    } else {
      unsigned int pw = (unsigned)f2bf(o[0]) | ((unsigned)f2bf(o[1]) << 16);
      *(unsigned int*)&dst[(size_t)wid * ldd + c * 2] = pw;
    }
  }
}

// ---------------- aggregation D=40 + log_softmax, fp32 out ----------------
__launch_bounds__(BLK)
__global__ void k_agg40(const unsigned short* __restrict__ g,
                        const float* __restrict__ dis, const float* __restrict__ bias,
                        const int* __restrict__ offs, const int* __restrict__ csr,
                        float* __restrict__ dst, int N) {
  int wid = (blockIdx.x * BLK + threadIdx.x) >> 6;
  int lane = threadIdx.x & 63;
  if (wid >= N) return;
  const int l5 = lane >> 5, c = lane & 31;
  const bool act = c < 20;
  float a0 = 0.f, a1 = 0.f;
  auto addrow = [&](int r) {
    if (act) {
      unsigned int w = *(const unsigned int*)&g[(size_t)r * 40 + c * 2];
      a0 += bf2f_lo(w); a1 += bf2f_hi(w);
    }
  };
  if (l5 == 0) addrow(wid);
  int beg = offs[wid], end = offs[wid + 1];
  for (int e0 = beg; e0 < end; e0 += 64) {
    int cnt = end - e0; if (cnt > 64) cnt = 64;
    int u = (lane < cnt) ? csr[e0 + lane] : 0;
    int j = 0;
    for (; j + 3 < cnt; j += 4) {
      int r0 = __shfl(u, j + l5);
      int r1 = __shfl(u, j + 2 + l5);
      addrow(r0); addrow(r1);
    }
    for (; j < cnt; j += 2) {
      int jj = j + l5;
      int r0 = __shfl(u, jj < cnt ? jj : j);
      if (jj < cnt) addrow(r0);
    }
  }
  a0 += __shfl_xor(a0, 32);
  a1 += __shfl_xor(a1, 32);

  if (l5 == 0) {
    float dv = dis[wid];
    float o0 = act ? dv * a0 + bias[c * 2]     : -__builtin_inff();
    float o1 = act ? dv * a1 + bias[c * 2 + 1] : -__builtin_inff();
    float mx = fmaxf(o0, o1);
    #pragma unroll
    for (int s = 16; s >= 1; s >>= 1) mx = fmaxf(mx, __shfl_down(mx, s, 32));
    mx = __shfl(mx, 0, 32);
    float ex = act ? (expf(o0 - mx) + expf(o1 - mx)) : 0.f;
    #pragma unroll
    for (int s = 16; s >= 1; s >>= 1) ex += __shfl_down(ex, s, 32);
    float ls = logf(__shfl(ex, 0, 32));
    if (act) {
      float2 r = make_float2(o0 - mx - ls, o1 - mx - ls);
      *(float2*)&dst[(size_t)wid * 40 + c * 2] = r;
    }
  }
}

// ---------------- launcher ----------------
extern "C" void kernel_launch(void* const* d_in, const int* in_sizes, int n_in,
                              void* d_out, int out_size, void* d_ws, size_t ws_size,
                              hipStream_t stream) {
  const float* x    = (const float*)d_in[0];
  const int*   ei   = (const int*)d_in[1];
  const float* eig  = (const float*)d_in[2];
  const float* W1   = (const float*)d_in[3];
  const float* b1   = (const float*)d_in[4];
  const float* W2   = (const float*)d_in[5];
  const float* b2   = (const float*)d_in[6];
  const float* linW = (const float*)d_in[7];
  const float* W3   = (const float*)d_in[8];
  const float* b3   = (const float*)d_in[9];
  float* out = (float*)d_out;

  const int N = in_sizes[0] / 512;
  const int E = in_sizes[1] / 2;

  char* ws = (char*)d_ws;
  size_t off = 0;
  auto alloc = [&](size_t bytes) { char* p = ws + off; off = ws_align(off + bytes); return p; };
  unsigned int* pk = (unsigned int*)alloc((size_t)E * 4);
  unsigned int* P  = (unsigned int*)alloc((size_t)E * 4);
  int*   csr    = (int*)alloc((size_t)E * 4);
  int*   offs   = (int*)alloc((size_t)(N + 1) * 4);
  int*   cnt    = (int*)alloc((size_t)NB * 256 * 4);
  int*   base   = (int*)alloc((size_t)NB * 256 * 4);
  int*   woffs  = (int*)alloc(257 * 4);
  float* dis    = (float*)alloc((size_t)N * 4);
  unsigned short* F   = (unsigned short*)alloc((size_t)N * 128 * 2);  // gemm1 out
  unsigned short* G   = (unsigned short*)alloc((size_t)N * 128 * 2);  // h1
  unsigned short* F2  = (unsigned short*)alloc((size_t)N * 64 * 2);   // conv2 out
  unsigned short* H2  = (unsigned short*)alloc((size_t)N * 64 * 2);   // conv2 agg out
  unsigned short* XP3 = (unsigned short*)alloc((size_t)N * 40 * 2);   // eig @ W3c
  unsigned short* F3  = (unsigned short*)alloc((size_t)N * 40 * 2);   // conv3 pre-agg
  unsigned short* WT1 = (unsigned short*)alloc(128 * 512 * 2);        // tile-major
  unsigned short* WT2 = (unsigned short*)alloc(64 * 128 * 2);
  unsigned short* W3aT = (unsigned short*)alloc(48 * 64 * 2);
  unsigned short* WT3c = (unsigned short*)alloc(48 * 128 * 2);

  const int nChunk = (E + NB - 1) / NB;
  const int NW = (N + 255) / 256;
  const int WTB = (76800 + BLK - 1) / BLK;
  const int gG1 = (N + 63) / 64;            // gemm1: 64 rows/block
  const int gX  = (N + 127) / 128;          // XP3 / mgemm blocks
  const int gA = (N + 3) / 4;

  k_pack_wt<<<NB + WTB, BLK, 0, stream>>>(ei, pk, cnt, E, nChunk,
                                          W1, W2, W3, WT1, WT2, W3aT);
  k_wscan_w3c<<<5, 256, 0, stream>>>(cnt, woffs, base, NB, E, linW, W3, WT3c);
  k_part_gemm1<<<gG1 + NB + gX, BLK, 0, stream>>>(pk, base, P, E, nChunk, x, WT1, F, N, gG1,
                                                  eig, WT3c, XP3);
  k_window_build<<<NW, BLK, 0, stream>>>(P, woffs, dis, offs, csr, N, E);

  // conv1 agg: h1 = relu(dis[v]*(sum du*g1[u] + dv*g1[v]) + b1)
  k_agg2<128, true, true><<<gA, BLK, 0, stream>>>(F, 128, dis, b1, offs, csr, G, 128, N);
  // conv2 GEMM
  k_mgemm2<<<gX, BLK, 0, stream>>>(G, WT2, dis, F2, N);
  // conv2 agg
  k_agg2<64, true, false><<<gA, BLK, 0, stream>>>(F2, 64, dis, b2, offs, csr, H2, 64, N);
  // conv3 GEMM (K=64, + XP3 fold)
  k_mgemm3b<<<gX, BLK, 0, stream>>>(H2, W3aT, XP3, dis, F3, N);
  // conv3 agg + log_softmax
  k_agg40<<<gA, BLK, 0, stream>>>(F3, dis, b3, offs, csr, out, N);
}